// Round 13
// baseline (304.079 us; speedup 1.0000x reference)
//
#include <hip/hip_runtime.h>

// N=50000 nodes, E=600000 edges, D=128, L=4 layers, G=128 graphs.
#define NN 50000
#define NE 600000
#define DIM 128
#define NLAYER 4
#define NGRAPH 128
#define SCAN_BLOCKS ((NN + 255) / 256)   // 196
#define POOL_SPLIT 4                     // blocks per graph in pool stage 1

typedef unsigned int u32;
typedef __attribute__((ext_vector_type(8))) short short8v;  // 8 x bf16 (4 VGPR)
typedef __attribute__((ext_vector_type(4))) float f32x4;

// pack two fp32 -> 2x bf16 (round-to-nearest-even)
__device__ __forceinline__ u32 bf2(float a, float b) {
    u32 ua = __float_as_uint(a);
    ua = (ua + 0x7fffu + ((ua >> 16) & 1u)) >> 16;
    u32 ub = __float_as_uint(b);
    ub = (ub + 0x7fffu + ((ub >> 16) & 1u)) >> 16;
    return ua | (ub << 16);
}
__device__ __forceinline__ unsigned short bf16r(float a) {
    u32 u = __float_as_uint(a);
    u = (u + 0x7fffu + ((u >> 16) & 1u)) >> 16;
    return (unsigned short)u;
}
__device__ __forceinline__ float bflo(u32 v) { return __uint_as_float(v << 16); }
__device__ __forceinline__ float bfhi(u32 v) { return __uint_as_float(v & 0xffff0000u); }

// ---------------- CSR build (edge structure only, once per launch) ----------

__global__ void zero2_kernel(int* __restrict__ a, int* __restrict__ b) {
    int i = blockIdx.x * 256 + threadIdx.x;
    if (i < NN) {
        a[i] = 0;
        b[i] = 0;
    }
}

__global__ void deg_kernel(const int* __restrict__ dst, int* __restrict__ deg) {
    int e = blockIdx.x * blockDim.x + threadIdx.x;
    if (e < NE) atomicAdd(&deg[dst[e]], 1);
}

__launch_bounds__(256)
__global__ void blocksum_kernel(const int* __restrict__ deg, int* __restrict__ bsum) {
    int i = blockIdx.x * 256 + threadIdx.x;
    int v = (i < NN) ? deg[i] : 0;
    #pragma unroll
    for (int o = 32; o > 0; o >>= 1) v += __shfl_xor(v, o);
    __shared__ int ws[4];
    int wid = threadIdx.x >> 6;
    if ((threadIdx.x & 63) == 0) ws[wid] = v;
    __syncthreads();
    if (threadIdx.x == 0) bsum[blockIdx.x] = ws[0] + ws[1] + ws[2] + ws[3];
}

__launch_bounds__(256)
__global__ void scanb_kernel(int* __restrict__ bsum) {
    __shared__ int s[256];
    int tid = threadIdx.x;
    int v = (tid < SCAN_BLOCKS) ? bsum[tid] : 0;
    s[tid] = v;
    __syncthreads();
    for (int o = 1; o < 256; o <<= 1) {
        int t = (tid >= o) ? s[tid - o] : 0;
        __syncthreads();
        s[tid] += t;
        __syncthreads();
    }
    if (tid < SCAN_BLOCKS) bsum[tid] = s[tid] - v;  // exclusive
}

__launch_bounds__(256)
__global__ void rowptr_kernel(const int* __restrict__ deg, const int* __restrict__ bsum,
                              int* __restrict__ row_ptr, float* __restrict__ dinv) {
    __shared__ int s[256];
    int tid = threadIdx.x;
    int i = blockIdx.x * 256 + tid;
    int d = (i < NN) ? deg[i] : 0;
    s[tid] = d;
    __syncthreads();
    for (int o = 1; o < 256; o <<= 1) {
        int t = (tid >= o) ? s[tid - o] : 0;
        __syncthreads();
        s[tid] += t;
        __syncthreads();
    }
    if (i < NN) {
        row_ptr[i] = bsum[blockIdx.x] + s[tid] - d;  // exclusive prefix
        dinv[i] = rsqrtf((float)d + 1.0f);           // +1 self-loop
    }
    if (i == 0) row_ptr[NN] = NE;
}

__global__ void fill_kernel(const int* __restrict__ src, const int* __restrict__ dst,
                            const int* __restrict__ row_ptr, int* __restrict__ cnt,
                            int* __restrict__ csr_src) {
    int e = blockIdx.x * blockDim.x + threadIdx.x;
    if (e >= NE) return;
    int d = dst[e];
    int pos = row_ptr[d] + atomicAdd(&cnt[d], 1);
    csr_src[pos] = src[e];
}

// ---------------- one-time conversions (fused) -------------------------------

__global__ void conv_kernel(const float* __restrict__ x, u32* __restrict__ xb,
                            const float* __restrict__ W, unsigned short* __restrict__ WT) {
    int t = blockIdx.x * 256 + threadIdx.x;
    if (t < NN * 64) {
        float2 v = ((const float2*)x)[t];
        xb[t] = bf2(v.x, v.y);
    } else {
        t -= NN * 64;
        if (t < NLAYER * DIM * DIM) {
            int l = t >> 14;
            int rem = t & 16383;
            int k = rem >> 7, n = rem & 127;
            WT[(size_t)l * 16384 + n * 128 + k] = bf16r(W[(size_t)l * 16384 + k * 128 + n]);
        }
    }
}

// ---------------- GEMM via MFMA, LDS-free ------------------------------------
// H2[N,128](bf16) = (Xb @ W) * dinv[row]. 256 threads = 4 waves, 64-row tile.
// A and B fragments loaded DIRECTLY from global; W is 32 KB L2-hot, X streamed.
// Layouts (m89-verified): A row=lane&15, k=8*(lane>>4)+j; B col=lane&15,
// same k; D col=lane&15, row=4*(lane>>4)+reg.

__launch_bounds__(256)
__global__ void gemm_mfma_kernel(const u32* __restrict__ Xb, const unsigned short* __restrict__ WTl,
                                 const float* __restrict__ dinv,
                                 unsigned short* __restrict__ H2s, int nrows) {
    const int tid = threadIdx.x;
    const int wave = tid >> 6;
    const int lane = tid & 63;
    const int lrow = lane & 15;   // A row / B col within tile
    const int kg = lane >> 4;     // k-group: k = 32*kc + 8*kg + j

    const int row = blockIdx.x * 64 + wave * 16 + lrow;
    const int arow = min(row, nrows - 1);  // clamp OOB loads; stores guarded

    const short8v* xrow = (const short8v*)(Xb + (size_t)arow * 64);
    short8v a[4];
    #pragma unroll
    for (int kc = 0; kc < 4; ++kc) a[kc] = xrow[kc * 4 + kg];

    f32x4 acc[8];
    #pragma unroll
    for (int t = 0; t < 8; ++t) acc[t] = (f32x4){0.f, 0.f, 0.f, 0.f};

    #pragma unroll
    for (int t = 0; t < 8; ++t) {
        const short8v* wrow = (const short8v*)(WTl + (size_t)(t * 16 + lrow) * 128);
        #pragma unroll
        for (int kc = 0; kc < 4; ++kc) {
            short8v bfrag = wrow[kc * 4 + kg];
            acc[t] = __builtin_amdgcn_mfma_f32_16x16x32_bf16(a[kc], bfrag, acc[t], 0, 0, 0);
        }
    }

    const int rbase = blockIdx.x * 64 + wave * 16 + 4 * kg;
    #pragma unroll
    for (int r = 0; r < 4; ++r) {
        int orow = rbase + r;
        if (orow < nrows) {
            float dv = dinv[orow];
            #pragma unroll
            for (int t = 0; t < 8; ++t)
                H2s[(size_t)orow * DIM + t * 16 + lrow] = bf16r(acc[t][r] * dv);
        }
    }
}

// ---------------- fused gather + residual + bias + LayerNorm + ReLU ---------
// R10-proven version: TWO nodes per wave (32-lane halves); lane owns 4 dims
// via uint2 (8B) loads. Edge loop unrolled x4. Width-32 LN reduce.

__launch_bounds__(256)
__global__ void gather_ln_kernel(const u32* __restrict__ h2u, const float* __restrict__ dinv,
                                 const int* __restrict__ row_ptr, const int* __restrict__ csr_src,
                                 const float* __restrict__ bl, const float* __restrict__ gamma,
                                 const float* __restrict__ beta, u32* __restrict__ xb) {
    int node = blockIdx.x * 8 + (threadIdx.x >> 5);
    int l = threadIdx.x & 31;
    int beg = row_ptr[node];
    int deg = row_ptr[node + 1] - beg;

    int myidx = (l < deg) ? csr_src[beg + l] : 0;

    uint2 sv = ((const uint2*)(h2u + (size_t)node * 64))[l];  // self-loop term
    float a0 = bflo(sv.x), a1 = bfhi(sv.x), a2 = bflo(sv.y), a3 = bfhi(sv.y);
    float c0 = 0.f, c1 = 0.f, c2 = 0.f, c3 = 0.f;

    int e = 0;
    for (; e + 4 <= deg; e += 4) {
        int sn0 = (e     < 32) ? __shfl(myidx, e,     32) : csr_src[beg + e];
        int sn1 = (e + 1 < 32) ? __shfl(myidx, e + 1, 32) : csr_src[beg + e + 1];
        int sn2 = (e + 2 < 32) ? __shfl(myidx, e + 2, 32) : csr_src[beg + e + 2];
        int sn3 = (e + 3 < 32) ? __shfl(myidx, e + 3, 32) : csr_src[beg + e + 3];
        uint2 v0 = ((const uint2*)(h2u + (size_t)sn0 * 64))[l];
        uint2 v1 = ((const uint2*)(h2u + (size_t)sn1 * 64))[l];
        uint2 v2 = ((const uint2*)(h2u + (size_t)sn2 * 64))[l];
        uint2 v3 = ((const uint2*)(h2u + (size_t)sn3 * 64))[l];
        a0 += bflo(v0.x); a1 += bfhi(v0.x); a2 += bflo(v0.y); a3 += bfhi(v0.y);
        c0 += bflo(v1.x); c1 += bfhi(v1.x); c2 += bflo(v1.y); c3 += bfhi(v1.y);
        a0 += bflo(v2.x); a1 += bfhi(v2.x); a2 += bflo(v2.y); a3 += bfhi(v2.y);
        c0 += bflo(v3.x); c1 += bfhi(v3.x); c2 += bflo(v3.y); c3 += bfhi(v3.y);
    }
    for (; e < deg; ++e) {
        int sn = (e < 32) ? __shfl(myidx, e, 32) : csr_src[beg + e];
        uint2 v = ((const uint2*)(h2u + (size_t)sn * 64))[l];
        a0 += bflo(v.x); a1 += bfhi(v.x); a2 += bflo(v.y); a3 += bfhi(v.y);
    }
    a0 += c0; a1 += c1; a2 += c2; a3 += c3;

    float dn = dinv[node];
    uint2 xv = ((const uint2*)(xb + (size_t)node * 64))[l];
    float4 bv = ((const float4*)bl)[l];
    float ax = bflo(xv.x) + a0 * dn + bv.x;
    float ay = bfhi(xv.x) + a1 * dn + bv.y;
    float az = bflo(xv.y) + a2 * dn + bv.z;
    float aw = bfhi(xv.y) + a3 * dn + bv.w;

    float sum = ax + ay + az + aw;
    float sq = ax * ax + ay * ay + az * az + aw * aw;
    #pragma unroll
    for (int o = 16; o > 0; o >>= 1) {
        sum += __shfl_xor(sum, o, 32);
        sq += __shfl_xor(sq, o, 32);
    }
    float mean = sum * (1.0f / DIM);
    float var = sq * (1.0f / DIM) - mean * mean;
    float rstd = rsqrtf(var + 1e-5f);
    float4 g = ((const float4*)gamma)[l];
    float4 bt = ((const float4*)beta)[l];
    float ox = fmaxf((ax - mean) * rstd * g.x + bt.x, 0.f);
    float oy = fmaxf((ay - mean) * rstd * g.y + bt.y, 0.f);
    float oz = fmaxf((az - mean) * rstd * g.z + bt.z, 0.f);
    float ow = fmaxf((aw - mean) * rstd * g.w + bt.w, 0.f);
    uint2 o;
    o.x = bf2(ox, oy);
    o.y = bf2(oz, ow);
    ((uint2*)(xb + (size_t)node * 64))[l] = o;
}

// ---------------- global mean pool (batch is SORTED -> segments) ------------

__global__ void bounds_kernel(const int* __restrict__ batch, int* __restrict__ bounds) {
    int g = threadIdx.x;
    if (g > NGRAPH) return;
    int lo = 0, hi = NN;
    while (lo < hi) {
        int mid = (lo + hi) >> 1;
        if (batch[mid] < g) lo = mid + 1; else hi = mid;
    }
    bounds[g] = lo;
}

__launch_bounds__(256)
__global__ void pool1_kernel(const u32* __restrict__ xb, const int* __restrict__ bounds,
                             float* __restrict__ partials) {
    __shared__ float part[3][DIM];
    int g = blockIdx.x >> 2;
    int q = blockIdx.x & 3;
    int beg = bounds[g], end = bounds[g + 1];
    int len = end - beg;
    int qbeg = beg + (int)(((long long)len * q) >> 2);
    int qend = beg + (int)(((long long)len * (q + 1)) >> 2);
    int grp = threadIdx.x >> 6;
    int lane = threadIdx.x & 63;
    float sx = 0.f, sy = 0.f;
    for (int r = qbeg + grp; r < qend; r += 4) {
        u32 v = xb[(size_t)r * 64 + lane];
        sx += bflo(v);
        sy += bfhi(v);
    }
    if (grp > 0) {
        part[grp - 1][lane * 2 + 0] = sx;
        part[grp - 1][lane * 2 + 1] = sy;
    }
    __syncthreads();
    if (grp == 0) {
        sx += part[0][lane * 2] + part[1][lane * 2] + part[2][lane * 2];
        sy += part[0][lane * 2 + 1] + part[1][lane * 2 + 1] + part[2][lane * 2 + 1];
        partials[(size_t)blockIdx.x * DIM + lane * 2 + 0] = sx;
        partials[(size_t)blockIdx.x * DIM + lane * 2 + 1] = sy;
    }
}

__launch_bounds__(256)
__global__ void pool2_kernel(const float* __restrict__ partials, const int* __restrict__ bounds,
                             float* __restrict__ out) {
    int t = blockIdx.x * 256 + threadIdx.x;
    if (t >= NGRAPH * DIM) return;
    int g = t >> 7;
    int d = t & 127;
    float s = partials[(size_t)(4 * g + 0) * DIM + d] + partials[(size_t)(4 * g + 1) * DIM + d] +
              partials[(size_t)(4 * g + 2) * DIM + d] + partials[(size_t)(4 * g + 3) * DIM + d];
    float cntf = (float)(bounds[g + 1] - bounds[g]);
    out[t] = s / fmaxf(cntf, 1.0f);
}

// ---------------- launch ----------------------------------------------------

extern "C" void kernel_launch(void* const* d_in, const int* in_sizes, int n_in,
                              void* d_out, int out_size, void* d_ws, size_t ws_size,
                              hipStream_t stream) {
    const float* x     = (const float*)d_in[0];
    const int*   ei    = (const int*)d_in[1];
    const int*   batch = (const int*)d_in[2];
    const float* W     = (const float*)d_in[3];
    const float* b     = (const float*)d_in[4];
    const float* gamma = (const float*)d_in[5];
    const float* beta  = (const float*)d_in[6];
    float* out = (float*)d_out;

    const int* srcE = ei;        // edge_index[0]
    const int* dstE = ei + NE;   // edge_index[1]

    // workspace layout
    char* p = (char*)d_ws;
    u32*   xb      = (u32*)p;    p += (size_t)NN * (DIM / 2) * sizeof(u32);    // 12.8 MB
    unsigned short* h2s = (unsigned short*)p; p += (size_t)NN * DIM * sizeof(unsigned short); // 12.8 MB
    unsigned short* WT  = (unsigned short*)p; p += (size_t)NLAYER * DIM * DIM * sizeof(unsigned short);
    float* dinv    = (float*)p;  p += (size_t)NN * sizeof(float);
    int*   deg     = (int*)p;    p += (size_t)NN * sizeof(int);
    int*   ccnt    = (int*)p;    p += (size_t)NN * sizeof(int);
    int*   row_ptr = (int*)p;    p += (size_t)(NN + 1) * sizeof(int);
    int*   csr_src = (int*)p;    p += (size_t)NE * sizeof(int);
    int*   bounds  = (int*)p;    p += (size_t)(NGRAPH + 1) * sizeof(int);
    int*   bsum    = (int*)p;    p += (size_t)SCAN_BLOCKS * sizeof(int);
    float* partials = (float*)p; p += (size_t)NGRAPH * POOL_SPLIT * DIM * sizeof(float);

    // CSR build
    zero2_kernel<<<SCAN_BLOCKS, 256, 0, stream>>>(deg, ccnt);
    deg_kernel<<<(NE + 255) / 256, 256, 0, stream>>>(dstE, deg);
    blocksum_kernel<<<SCAN_BLOCKS, 256, 0, stream>>>(deg, bsum);
    scanb_kernel<<<1, 256, 0, stream>>>(bsum);
    rowptr_kernel<<<SCAN_BLOCKS, 256, 0, stream>>>(deg, bsum, row_ptr, dinv);
    fill_kernel<<<(NE + 255) / 256, 256, 0, stream>>>(srcE, dstE, row_ptr, ccnt, csr_src);
    bounds_kernel<<<1, 256, 0, stream>>>(batch, bounds);

    // one-time conversions (fused)
    conv_kernel<<<(NN * 64 + NLAYER * DIM * DIM + 255) / 256, 256, 0, stream>>>(x, xb, W, WT);

    for (int l = 0; l < NLAYER; ++l) {
        gemm_mfma_kernel<<<(NN + 63) / 64, 256, 0, stream>>>(
            xb, WT + (size_t)l * DIM * DIM, dinv, h2s, NN);
        gather_ln_kernel<<<NN / 8, 256, 0, stream>>>(
            (const u32*)h2s, dinv, row_ptr, csr_src,
            b + l * DIM, gamma + l * DIM, beta + l * DIM, xb);
    }

    pool1_kernel<<<NGRAPH * POOL_SPLIT, 256, 0, stream>>>(xb, bounds, partials);
    pool2_kernel<<<(NGRAPH * DIM + 255) / 256, 256, 0, stream>>>(partials, bounds, out);
}

// Round 14
// 245.067 us; speedup vs baseline: 1.2408x; 1.2408x over previous
//
#include <hip/hip_runtime.h>

// N=50000 nodes, E=600000 edges, D=128, L=4 layers, G=128 graphs.
#define NN 50000
#define NE 600000
#define DIM 128
#define NLAYER 4
#define NGRAPH 128
#define SCAN_BLOCKS ((NN + 255) / 256)   // 196
#define XS_STRIDE 136                    // bf16 elems per LDS row (128 + 8 pad)
#define POOL_SPLIT 4                     // blocks per graph in pool stage 1

typedef unsigned int u32;
typedef __attribute__((ext_vector_type(8))) short short8v;  // 8 x bf16 (4 VGPR)
typedef __attribute__((ext_vector_type(4))) float f32x4;

// pack two fp32 -> 2x bf16 (round-to-nearest-even)
__device__ __forceinline__ u32 bf2(float a, float b) {
    u32 ua = __float_as_uint(a);
    ua = (ua + 0x7fffu + ((ua >> 16) & 1u)) >> 16;
    u32 ub = __float_as_uint(b);
    ub = (ub + 0x7fffu + ((ub >> 16) & 1u)) >> 16;
    return ua | (ub << 16);
}
__device__ __forceinline__ unsigned short bf16r(float a) {
    u32 u = __float_as_uint(a);
    u = (u + 0x7fffu + ((u >> 16) & 1u)) >> 16;
    return (unsigned short)u;
}
__device__ __forceinline__ float bflo(u32 v) { return __uint_as_float(v << 16); }
__device__ __forceinline__ float bfhi(u32 v) { return __uint_as_float(v & 0xffff0000u); }

// ---------------- CSR build (edge structure only, once per launch) ----------

__global__ void zero2_kernel(int* __restrict__ a, int* __restrict__ b) {
    int i = blockIdx.x * 256 + threadIdx.x;
    if (i < NN) {
        a[i] = 0;
        b[i] = 0;
    }
}

__global__ void deg_kernel(const int* __restrict__ dst, int* __restrict__ deg) {
    int e = blockIdx.x * blockDim.x + threadIdx.x;
    if (e < NE) atomicAdd(&deg[dst[e]], 1);
}

__launch_bounds__(256)
__global__ void blocksum_kernel(const int* __restrict__ deg, int* __restrict__ bsum) {
    int i = blockIdx.x * 256 + threadIdx.x;
    int v = (i < NN) ? deg[i] : 0;
    #pragma unroll
    for (int o = 32; o > 0; o >>= 1) v += __shfl_xor(v, o);
    __shared__ int ws[4];
    int wid = threadIdx.x >> 6;
    if ((threadIdx.x & 63) == 0) ws[wid] = v;
    __syncthreads();
    if (threadIdx.x == 0) bsum[blockIdx.x] = ws[0] + ws[1] + ws[2] + ws[3];
}

__launch_bounds__(256)
__global__ void scanb_kernel(int* __restrict__ bsum) {
    __shared__ int s[256];
    int tid = threadIdx.x;
    int v = (tid < SCAN_BLOCKS) ? bsum[tid] : 0;
    s[tid] = v;
    __syncthreads();
    for (int o = 1; o < 256; o <<= 1) {
        int t = (tid >= o) ? s[tid - o] : 0;
        __syncthreads();
        s[tid] += t;
        __syncthreads();
    }
    if (tid < SCAN_BLOCKS) bsum[tid] = s[tid] - v;  // exclusive
}

__launch_bounds__(256)
__global__ void rowptr_kernel(const int* __restrict__ deg, const int* __restrict__ bsum,
                              int* __restrict__ row_ptr, float* __restrict__ dinv) {
    __shared__ int s[256];
    int tid = threadIdx.x;
    int i = blockIdx.x * 256 + tid;
    int d = (i < NN) ? deg[i] : 0;
    s[tid] = d;
    __syncthreads();
    for (int o = 1; o < 256; o <<= 1) {
        int t = (tid >= o) ? s[tid - o] : 0;
        __syncthreads();
        s[tid] += t;
        __syncthreads();
    }
    if (i < NN) {
        row_ptr[i] = bsum[blockIdx.x] + s[tid] - d;  // exclusive prefix
        dinv[i] = rsqrtf((float)d + 1.0f);           // +1 self-loop
    }
    if (i == 0) row_ptr[NN] = NE;
}

__global__ void fill_kernel(const int* __restrict__ src, const int* __restrict__ dst,
                            const int* __restrict__ row_ptr, int* __restrict__ cnt,
                            int* __restrict__ csr_src) {
    int e = blockIdx.x * blockDim.x + threadIdx.x;
    if (e >= NE) return;
    int d = dst[e];
    int pos = row_ptr[d] + atomicAdd(&cnt[d], 1);
    csr_src[pos] = src[e];
}

// ---------------- one-time conversions (fused) -------------------------------

__global__ void conv_kernel(const float* __restrict__ x, u32* __restrict__ xb,
                            const float* __restrict__ W, unsigned short* __restrict__ WT) {
    int t = blockIdx.x * 256 + threadIdx.x;
    if (t < NN * 64) {
        float2 v = ((const float2*)x)[t];
        xb[t] = bf2(v.x, v.y);
    } else {
        t -= NN * 64;
        if (t < NLAYER * DIM * DIM) {
            int l = t >> 14;
            int rem = t & 16383;
            int k = rem >> 7, n = rem & 127;
            WT[(size_t)l * 16384 + n * 128 + k] = bf16r(W[(size_t)l * 16384 + k * 128 + n]);
        }
    }
}

// ---------------- GEMM via MFMA, hybrid staging ------------------------------
// H2[N,128](bf16) = (Xb @ W) * dinv[row]. 256 threads = 4 waves, 64-row tile.
// W staged in LDS (proven necessary: LDS-free B-loads cost +39 µs, R11/R12);
// A fragments loaded directly global->reg (each element reused 8x in-reg;
// X-through-LDS was pure overhead). LDS 34.8 KB -> 4 blocks/CU.
// Layouts (m89-verified): A row=lane&15, k=8*(lane>>4)+j; B col=lane&15,
// same k; D col=lane&15, row=4*(lane>>4)+reg.

__launch_bounds__(256)
__global__ void gemm_mfma_kernel(const u32* __restrict__ Xb, const unsigned short* __restrict__ WTl,
                                 const float* __restrict__ dinv,
                                 unsigned short* __restrict__ H2s, int nrows) {
    __shared__ __align__(16) unsigned short wt[128 * XS_STRIDE];   // 34816 B
    const int tid = threadIdx.x;
    const int wave = tid >> 6;
    const int lane = tid & 63;
    const int lrow = lane & 15;   // A row / B col within tile
    const int kg = lane >> 4;     // k-group: k = 32*kc + 8*kg + j

    // stage WT: 128 rows x 16 uint4 (LDS row stride 17 uint4)
    {
        const uint4* wg = (const uint4*)WTl;
        uint4* wt4 = (uint4*)wt;
        #pragma unroll
        for (int i = 0; i < 8; ++i) {
            int idx = i * 256 + tid;          // 0..2047
            int r = idx >> 4, c = idx & 15;
            wt4[r * 17 + c] = wg[idx];
        }
    }

    // A fragments direct from global (issue before barrier to overlap)
    const int row = blockIdx.x * 64 + wave * 16 + lrow;
    const int arow = min(row, nrows - 1);  // clamp OOB loads; stores guarded
    const short8v* xrow = (const short8v*)(Xb + (size_t)arow * 64);
    short8v a[4];
    #pragma unroll
    for (int kc = 0; kc < 4; ++kc) a[kc] = xrow[kc * 4 + kg];

    __syncthreads();

    f32x4 acc[8];
    #pragma unroll
    for (int t = 0; t < 8; ++t) acc[t] = (f32x4){0.f, 0.f, 0.f, 0.f};

    #pragma unroll
    for (int t = 0; t < 8; ++t) {
        #pragma unroll
        for (int kc = 0; kc < 4; ++kc) {
            short8v bfrag = *(const short8v*)&wt[(t * 16 + lrow) * XS_STRIDE + kc * 32 + kg * 8];
            acc[t] = __builtin_amdgcn_mfma_f32_16x16x32_bf16(a[kc], bfrag, acc[t], 0, 0, 0);
        }
    }

    // epilogue: scale by dinv, store bf16 (D: col=lrow, row=4*kg+r)
    const int rbase = blockIdx.x * 64 + wave * 16 + 4 * kg;
    #pragma unroll
    for (int r = 0; r < 4; ++r) {
        int orow = rbase + r;
        if (orow < nrows) {
            float dv = dinv[orow];
            #pragma unroll
            for (int t = 0; t < 8; ++t)
                H2s[(size_t)orow * DIM + t * 16 + lrow] = bf16r(acc[t][r] * dv);
        }
    }
}

// ---------------- fused gather + residual + bias + LayerNorm + ReLU ---------
// R11-proven variant (beat 2-node by ~10 µs): FOUR nodes per wave (16-lane
// groups); lane owns 8 dims via uint4 (16B). Edge loop unrolled x4 -> up to
// 16 rows in flight per wave. Width-16 LN reduce. NN = 3125 blocks x 16.

__launch_bounds__(256)
__global__ void gather_ln_kernel(const u32* __restrict__ h2u, const float* __restrict__ dinv,
                                 const int* __restrict__ row_ptr, const int* __restrict__ csr_src,
                                 const float* __restrict__ bl, const float* __restrict__ gamma,
                                 const float* __restrict__ beta, u32* __restrict__ xb) {
    int node = blockIdx.x * 16 + (threadIdx.x >> 4);
    int l = threadIdx.x & 15;
    int beg = row_ptr[node];
    int deg = row_ptr[node + 1] - beg;

    // preload up to 16 neighbor indices, one per lane of this 16-lane group
    int myidx = (l < deg) ? csr_src[beg + l] : 0;

    const uint4* h4 = (const uint4*)h2u;   // row = 16 uint4
    uint4 sv = h4[(size_t)node * 16 + l];  // self-loop term
    float a0 = bflo(sv.x), a1 = bfhi(sv.x), a2 = bflo(sv.y), a3 = bfhi(sv.y);
    float a4 = bflo(sv.z), a5 = bfhi(sv.z), a6 = bflo(sv.w), a7 = bfhi(sv.w);
    float c0 = 0.f, c1 = 0.f, c2 = 0.f, c3 = 0.f, c4 = 0.f, c5 = 0.f, c6 = 0.f, c7 = 0.f;

    int e = 0;
    for (; e + 4 <= deg; e += 4) {
        int sn0 = (e     < 16) ? __shfl(myidx, e,     16) : csr_src[beg + e];
        int sn1 = (e + 1 < 16) ? __shfl(myidx, e + 1, 16) : csr_src[beg + e + 1];
        int sn2 = (e + 2 < 16) ? __shfl(myidx, e + 2, 16) : csr_src[beg + e + 2];
        int sn3 = (e + 3 < 16) ? __shfl(myidx, e + 3, 16) : csr_src[beg + e + 3];
        uint4 v0 = h4[(size_t)sn0 * 16 + l];
        uint4 v1 = h4[(size_t)sn1 * 16 + l];
        uint4 v2 = h4[(size_t)sn2 * 16 + l];
        uint4 v3 = h4[(size_t)sn3 * 16 + l];
        a0 += bflo(v0.x); a1 += bfhi(v0.x); a2 += bflo(v0.y); a3 += bfhi(v0.y);
        a4 += bflo(v0.z); a5 += bfhi(v0.z); a6 += bflo(v0.w); a7 += bfhi(v0.w);
        c0 += bflo(v1.x); c1 += bfhi(v1.x); c2 += bflo(v1.y); c3 += bfhi(v1.y);
        c4 += bflo(v1.z); c5 += bfhi(v1.z); c6 += bflo(v1.w); c7 += bfhi(v1.w);
        a0 += bflo(v2.x); a1 += bfhi(v2.x); a2 += bflo(v2.y); a3 += bfhi(v2.y);
        a4 += bflo(v2.z); a5 += bfhi(v2.z); a6 += bflo(v2.w); a7 += bfhi(v2.w);
        c0 += bflo(v3.x); c1 += bfhi(v3.x); c2 += bflo(v3.y); c3 += bfhi(v3.y);
        c4 += bflo(v3.z); c5 += bfhi(v3.z); c6 += bflo(v3.w); c7 += bfhi(v3.w);
    }
    for (; e < deg; ++e) {
        int sn = (e < 16) ? __shfl(myidx, e, 16) : csr_src[beg + e];
        uint4 v = h4[(size_t)sn * 16 + l];
        a0 += bflo(v.x); a1 += bfhi(v.x); a2 += bflo(v.y); a3 += bfhi(v.y);
        a4 += bflo(v.z); a5 += bfhi(v.z); a6 += bflo(v.w); a7 += bfhi(v.w);
    }
    a0 += c0; a1 += c1; a2 += c2; a3 += c3;
    a4 += c4; a5 += c5; a6 += c6; a7 += c7;

    float dn = dinv[node];
    uint4 xv = ((const uint4*)xb)[(size_t)node * 16 + l];
    float4 bv0 = ((const float4*)bl)[2 * l];
    float4 bv1 = ((const float4*)bl)[2 * l + 1];
    float e0 = bflo(xv.x) + a0 * dn + bv0.x;
    float e1 = bfhi(xv.x) + a1 * dn + bv0.y;
    float e2 = bflo(xv.y) + a2 * dn + bv0.z;
    float e3 = bfhi(xv.y) + a3 * dn + bv0.w;
    float e4 = bflo(xv.z) + a4 * dn + bv1.x;
    float e5 = bfhi(xv.z) + a5 * dn + bv1.y;
    float e6 = bflo(xv.w) + a6 * dn + bv1.z;
    float e7 = bfhi(xv.w) + a7 * dn + bv1.w;

    float sum = e0 + e1 + e2 + e3 + e4 + e5 + e6 + e7;
    float sq = e0 * e0 + e1 * e1 + e2 * e2 + e3 * e3 + e4 * e4 + e5 * e5 + e6 * e6 + e7 * e7;
    #pragma unroll
    for (int o = 8; o > 0; o >>= 1) {
        sum += __shfl_xor(sum, o, 16);
        sq += __shfl_xor(sq, o, 16);
    }
    float mean = sum * (1.0f / DIM);
    float var = sq * (1.0f / DIM) - mean * mean;
    float rstd = rsqrtf(var + 1e-5f);
    float4 g0 = ((const float4*)gamma)[2 * l];
    float4 g1 = ((const float4*)gamma)[2 * l + 1];
    float4 t0 = ((const float4*)beta)[2 * l];
    float4 t1 = ((const float4*)beta)[2 * l + 1];
    float o0 = fmaxf((e0 - mean) * rstd * g0.x + t0.x, 0.f);
    float o1 = fmaxf((e1 - mean) * rstd * g0.y + t0.y, 0.f);
    float o2 = fmaxf((e2 - mean) * rstd * g0.z + t0.z, 0.f);
    float o3 = fmaxf((e3 - mean) * rstd * g0.w + t0.w, 0.f);
    float o4 = fmaxf((e4 - mean) * rstd * g1.x + t1.x, 0.f);
    float o5 = fmaxf((e5 - mean) * rstd * g1.y + t1.y, 0.f);
    float o6 = fmaxf((e6 - mean) * rstd * g1.z + t1.z, 0.f);
    float o7 = fmaxf((e7 - mean) * rstd * g1.w + t1.w, 0.f);
    uint4 ov;
    ov.x = bf2(o0, o1);
    ov.y = bf2(o2, o3);
    ov.z = bf2(o4, o5);
    ov.w = bf2(o6, o7);
    ((uint4*)xb)[(size_t)node * 16 + l] = ov;
}

// ---------------- global mean pool (batch is SORTED -> segments) ------------

__global__ void bounds_kernel(const int* __restrict__ batch, int* __restrict__ bounds) {
    int g = threadIdx.x;
    if (g > NGRAPH) return;
    int lo = 0, hi = NN;
    while (lo < hi) {
        int mid = (lo + hi) >> 1;
        if (batch[mid] < g) lo = mid + 1; else hi = mid;
    }
    bounds[g] = lo;
}

__launch_bounds__(256)
__global__ void pool1_kernel(const u32* __restrict__ xb, const int* __restrict__ bounds,
                             float* __restrict__ partials) {
    __shared__ float part[3][DIM];
    int g = blockIdx.x >> 2;
    int q = blockIdx.x & 3;
    int beg = bounds[g], end = bounds[g + 1];
    int len = end - beg;
    int qbeg = beg + (int)(((long long)len * q) >> 2);
    int qend = beg + (int)(((long long)len * (q + 1)) >> 2);
    int grp = threadIdx.x >> 6;
    int lane = threadIdx.x & 63;
    float sx = 0.f, sy = 0.f;
    for (int r = qbeg + grp; r < qend; r += 4) {
        u32 v = xb[(size_t)r * 64 + lane];
        sx += bflo(v);
        sy += bfhi(v);
    }
    if (grp > 0) {
        part[grp - 1][lane * 2 + 0] = sx;
        part[grp - 1][lane * 2 + 1] = sy;
    }
    __syncthreads();
    if (grp == 0) {
        sx += part[0][lane * 2] + part[1][lane * 2] + part[2][lane * 2];
        sy += part[0][lane * 2 + 1] + part[1][lane * 2 + 1] + part[2][lane * 2 + 1];
        partials[(size_t)blockIdx.x * DIM + lane * 2 + 0] = sx;
        partials[(size_t)blockIdx.x * DIM + lane * 2 + 1] = sy;
    }
}

__launch_bounds__(256)
__global__ void pool2_kernel(const float* __restrict__ partials, const int* __restrict__ bounds,
                             float* __restrict__ out) {
    int t = blockIdx.x * 256 + threadIdx.x;
    if (t >= NGRAPH * DIM) return;
    int g = t >> 7;
    int d = t & 127;
    float s = partials[(size_t)(4 * g + 0) * DIM + d] + partials[(size_t)(4 * g + 1) * DIM + d] +
              partials[(size_t)(4 * g + 2) * DIM + d] + partials[(size_t)(4 * g + 3) * DIM + d];
    float cntf = (float)(bounds[g + 1] - bounds[g]);
    out[t] = s / fmaxf(cntf, 1.0f);
}

// ---------------- launch ----------------------------------------------------

extern "C" void kernel_launch(void* const* d_in, const int* in_sizes, int n_in,
                              void* d_out, int out_size, void* d_ws, size_t ws_size,
                              hipStream_t stream) {
    const float* x     = (const float*)d_in[0];
    const int*   ei    = (const int*)d_in[1];
    const int*   batch = (const int*)d_in[2];
    const float* W     = (const float*)d_in[3];
    const float* b     = (const float*)d_in[4];
    const float* gamma = (const float*)d_in[5];
    const float* beta  = (const float*)d_in[6];
    float* out = (float*)d_out;

    const int* srcE = ei;        // edge_index[0]
    const int* dstE = ei + NE;   // edge_index[1]

    // workspace layout
    char* p = (char*)d_ws;
    u32*   xb      = (u32*)p;    p += (size_t)NN * (DIM / 2) * sizeof(u32);    // 12.8 MB
    unsigned short* h2s = (unsigned short*)p; p += (size_t)NN * DIM * sizeof(unsigned short); // 12.8 MB
    unsigned short* WT  = (unsigned short*)p; p += (size_t)NLAYER * DIM * DIM * sizeof(unsigned short);
    float* dinv    = (float*)p;  p += (size_t)NN * sizeof(float);
    int*   deg     = (int*)p;    p += (size_t)NN * sizeof(int);
    int*   ccnt    = (int*)p;    p += (size_t)NN * sizeof(int);
    int*   row_ptr = (int*)p;    p += (size_t)(NN + 1) * sizeof(int);
    int*   csr_src = (int*)p;    p += (size_t)NE * sizeof(int);
    int*   bounds  = (int*)p;    p += (size_t)(NGRAPH + 1) * sizeof(int);
    int*   bsum    = (int*)p;    p += (size_t)SCAN_BLOCKS * sizeof(int);
    float* partials = (float*)p; p += (size_t)NGRAPH * POOL_SPLIT * DIM * sizeof(float);

    // CSR build
    zero2_kernel<<<SCAN_BLOCKS, 256, 0, stream>>>(deg, ccnt);
    deg_kernel<<<(NE + 255) / 256, 256, 0, stream>>>(dstE, deg);
    blocksum_kernel<<<SCAN_BLOCKS, 256, 0, stream>>>(deg, bsum);
    scanb_kernel<<<1, 256, 0, stream>>>(bsum);
    rowptr_kernel<<<SCAN_BLOCKS, 256, 0, stream>>>(deg, bsum, row_ptr, dinv);
    fill_kernel<<<(NE + 255) / 256, 256, 0, stream>>>(srcE, dstE, row_ptr, ccnt, csr_src);
    bounds_kernel<<<1, 256, 0, stream>>>(batch, bounds);

    // one-time conversions (fused)
    conv_kernel<<<(NN * 64 + NLAYER * DIM * DIM + 255) / 256, 256, 0, stream>>>(x, xb, W, WT);

    for (int l = 0; l < NLAYER; ++l) {
        gemm_mfma_kernel<<<(NN + 63) / 64, 256, 0, stream>>>(
            xb, WT + (size_t)l * DIM * DIM, dinv, h2s, NN);
        gather_ln_kernel<<<NN / 16, 256, 0, stream>>>(
            (const u32*)h2s, dinv, row_ptr, csr_src,
            b + l * DIM, gamma + l * DIM, beta + l * DIM, xb);
    }

    pool1_kernel<<<NGRAPH * POOL_SPLIT, 256, 0, stream>>>(xb, bounds, partials);
    pool2_kernel<<<(NGRAPH * DIM + 255) / 256, 256, 0, stream>>>(partials, bounds, out);
}

// Round 15
// 237.495 us; speedup vs baseline: 1.2804x; 1.0319x over previous
//
#include <hip/hip_runtime.h>

// N=50000 nodes, E=600000 edges, D=128, L=4 layers, G=128 graphs.
#define NN 50000
#define NE 600000
#define DIM 128
#define NLAYER 4
#define NGRAPH 128
#define SCAN_BLOCKS ((NN + 255) / 256)   // 196
#define XS_STRIDE 136                    // bf16 elems per LDS row (128 + 8 pad)
#define POOL_SPLIT 4                     // blocks per graph in pool stage 1

typedef unsigned int u32;
typedef __attribute__((ext_vector_type(8))) short short8v;  // 8 x bf16 (4 VGPR)
typedef __attribute__((ext_vector_type(4))) float f32x4;

// pack two fp32 -> 2x bf16 (round-to-nearest-even)
__device__ __forceinline__ u32 bf2(float a, float b) {
    u32 ua = __float_as_uint(a);
    ua = (ua + 0x7fffu + ((ua >> 16) & 1u)) >> 16;
    u32 ub = __float_as_uint(b);
    ub = (ub + 0x7fffu + ((ub >> 16) & 1u)) >> 16;
    return ua | (ub << 16);
}
__device__ __forceinline__ unsigned short bf16r(float a) {
    u32 u = __float_as_uint(a);
    u = (u + 0x7fffu + ((u >> 16) & 1u)) >> 16;
    return (unsigned short)u;
}
__device__ __forceinline__ float bflo(u32 v) { return __uint_as_float(v << 16); }
__device__ __forceinline__ float bfhi(u32 v) { return __uint_as_float(v & 0xffff0000u); }

// ---------------- prep: zero deg/ccnt + bf16 conversions (one launch) -------

__global__ void prep_kernel(const float* __restrict__ x, u32* __restrict__ xb,
                            const float* __restrict__ W, unsigned short* __restrict__ WT,
                            int* __restrict__ deg, int* __restrict__ ccnt) {
    int t = blockIdx.x * 256 + threadIdx.x;
    if (t < NN) {          // first 196 blocks also zero the CSR counters
        deg[t] = 0;
        ccnt[t] = 0;
    }
    if (t < NN * 64) {
        float2 v = ((const float2*)x)[t];
        xb[t] = bf2(v.x, v.y);
    } else {
        int u = t - NN * 64;
        if (u < NLAYER * DIM * DIM) {
            int l = u >> 14;
            int rem = u & 16383;
            int k = rem >> 7, n = rem & 127;
            WT[(size_t)l * 16384 + n * 128 + k] = bf16r(W[(size_t)l * 16384 + k * 128 + n]);
        }
    }
}

// ---------------- CSR build (edge structure only, once per launch) ----------

__global__ void deg_kernel(const int* __restrict__ dst, int* __restrict__ deg) {
    int e = blockIdx.x * blockDim.x + threadIdx.x;
    if (e < NE) atomicAdd(&deg[dst[e]], 1);
}

__launch_bounds__(256)
__global__ void blocksum_kernel(const int* __restrict__ deg, int* __restrict__ bsum) {
    int i = blockIdx.x * 256 + threadIdx.x;
    int v = (i < NN) ? deg[i] : 0;
    #pragma unroll
    for (int o = 32; o > 0; o >>= 1) v += __shfl_xor(v, o);
    __shared__ int ws[4];
    int wid = threadIdx.x >> 6;
    if ((threadIdx.x & 63) == 0) ws[wid] = v;
    __syncthreads();
    if (threadIdx.x == 0) bsum[blockIdx.x] = ws[0] + ws[1] + ws[2] + ws[3];
}

// block 0: exclusive scan of 196 block sums. block 1: graph segment bounds.
__launch_bounds__(256)
__global__ void scanb_bounds_kernel(int* __restrict__ bsum, const int* __restrict__ batch,
                                    int* __restrict__ bounds) {
    if (blockIdx.x == 0) {
        __shared__ int s[256];
        int tid = threadIdx.x;
        int v = (tid < SCAN_BLOCKS) ? bsum[tid] : 0;
        s[tid] = v;
        __syncthreads();
        for (int o = 1; o < 256; o <<= 1) {
            int t = (tid >= o) ? s[tid - o] : 0;
            __syncthreads();
            s[tid] += t;
            __syncthreads();
        }
        if (tid < SCAN_BLOCKS) bsum[tid] = s[tid] - v;  // exclusive
    } else {
        int g = threadIdx.x;
        if (g > NGRAPH) return;
        int lo = 0, hi = NN;
        while (lo < hi) {
            int mid = (lo + hi) >> 1;
            if (batch[mid] < g) lo = mid + 1; else hi = mid;
        }
        bounds[g] = lo;
    }
}

__launch_bounds__(256)
__global__ void rowptr_kernel(const int* __restrict__ deg, const int* __restrict__ bsum,
                              int* __restrict__ row_ptr, float* __restrict__ dinv) {
    __shared__ int s[256];
    int tid = threadIdx.x;
    int i = blockIdx.x * 256 + tid;
    int d = (i < NN) ? deg[i] : 0;
    s[tid] = d;
    __syncthreads();
    for (int o = 1; o < 256; o <<= 1) {
        int t = (tid >= o) ? s[tid - o] : 0;
        __syncthreads();
        s[tid] += t;
        __syncthreads();
    }
    if (i < NN) {
        row_ptr[i] = bsum[blockIdx.x] + s[tid] - d;  // exclusive prefix
        dinv[i] = rsqrtf((float)d + 1.0f);           // +1 self-loop
    }
    if (i == 0) row_ptr[NN] = NE;
}

__global__ void fill_kernel(const int* __restrict__ src, const int* __restrict__ dst,
                            const int* __restrict__ row_ptr, int* __restrict__ cnt,
                            int* __restrict__ csr_src) {
    int e = blockIdx.x * blockDim.x + threadIdx.x;
    if (e >= NE) return;
    int d = dst[e];
    int pos = row_ptr[d] + atomicAdd(&cnt[d], 1);
    csr_src[pos] = src[e];
}

// ---------------- GEMM via MFMA, hybrid staging ------------------------------
// H2[N,128](bf16) = (Xb @ W) * dinv[row]. 256 threads = 4 waves, 64-row tile.
// W staged in LDS (proven necessary: LDS-free B-loads cost +39 µs, R11/R12);
// A fragments loaded directly global->reg. LDS 34.8 KB -> 4 blocks/CU.
// Layouts (m89-verified): A row=lane&15, k=8*(lane>>4)+j; B col=lane&15,
// same k; D col=lane&15, row=4*(lane>>4)+reg.

__launch_bounds__(256)
__global__ void gemm_mfma_kernel(const u32* __restrict__ Xb, const unsigned short* __restrict__ WTl,
                                 const float* __restrict__ dinv,
                                 unsigned short* __restrict__ H2s, int nrows) {
    __shared__ __align__(16) unsigned short wt[128 * XS_STRIDE];   // 34816 B
    const int tid = threadIdx.x;
    const int wave = tid >> 6;
    const int lane = tid & 63;
    const int lrow = lane & 15;   // A row / B col within tile
    const int kg = lane >> 4;     // k-group: k = 32*kc + 8*kg + j

    // stage WT: 128 rows x 16 uint4 (LDS row stride 17 uint4)
    {
        const uint4* wg = (const uint4*)WTl;
        uint4* wt4 = (uint4*)wt;
        #pragma unroll
        for (int i = 0; i < 8; ++i) {
            int idx = i * 256 + tid;          // 0..2047
            int r = idx >> 4, c = idx & 15;
            wt4[r * 17 + c] = wg[idx];
        }
    }

    // A fragments direct from global (issued before barrier to overlap)
    const int row = blockIdx.x * 64 + wave * 16 + lrow;
    const int arow = min(row, nrows - 1);  // clamp OOB loads; stores guarded
    const short8v* xrow = (const short8v*)(Xb + (size_t)arow * 64);
    short8v a[4];
    #pragma unroll
    for (int kc = 0; kc < 4; ++kc) a[kc] = xrow[kc * 4 + kg];

    __syncthreads();

    f32x4 acc[8];
    #pragma unroll
    for (int t = 0; t < 8; ++t) acc[t] = (f32x4){0.f, 0.f, 0.f, 0.f};

    #pragma unroll
    for (int t = 0; t < 8; ++t) {
        #pragma unroll
        for (int kc = 0; kc < 4; ++kc) {
            short8v bfrag = *(const short8v*)&wt[(t * 16 + lrow) * XS_STRIDE + kc * 32 + kg * 8];
            acc[t] = __builtin_amdgcn_mfma_f32_16x16x32_bf16(a[kc], bfrag, acc[t], 0, 0, 0);
        }
    }

    const int rbase = blockIdx.x * 64 + wave * 16 + 4 * kg;
    #pragma unroll
    for (int r = 0; r < 4; ++r) {
        int orow = rbase + r;
        if (orow < nrows) {
            float dv = dinv[orow];
            #pragma unroll
            for (int t = 0; t < 8; ++t)
                H2s[(size_t)orow * DIM + t * 16 + lrow] = bf16r(acc[t][r] * dv);
        }
    }
}

// ---------------- fused gather + residual + bias + LayerNorm + ReLU ---------
// FOUR nodes per wave (16-lane groups); lane owns 8 dims via uint4 (16B).
// Edge loop unrolled x4 -> up to 16 rows in flight per wave.
// Index preload covers deg<=32 (P(deg>32|Poisson 12) ~ 2e-7): myidx0 for
// e<16, myidx1 for e<32; scalar fallback nearly never taken.

__launch_bounds__(256)
__global__ void gather_ln_kernel(const u32* __restrict__ h2u, const float* __restrict__ dinv,
                                 const int* __restrict__ row_ptr, const int* __restrict__ csr_src,
                                 const float* __restrict__ bl, const float* __restrict__ gamma,
                                 const float* __restrict__ beta, u32* __restrict__ xb) {
    int node = blockIdx.x * 16 + (threadIdx.x >> 4);
    int l = threadIdx.x & 15;
    int beg = row_ptr[node];
    int deg = row_ptr[node + 1] - beg;

    // preload up to 32 neighbor indices, two per lane of this 16-lane group
    int myidx0 = (l < deg) ? csr_src[beg + l] : 0;
    int myidx1 = (16 + l < deg) ? csr_src[beg + 16 + l] : 0;

    const uint4* h4 = (const uint4*)h2u;   // row = 16 uint4
    uint4 sv = h4[(size_t)node * 16 + l];  // self-loop term
    float a0 = bflo(sv.x), a1 = bfhi(sv.x), a2 = bflo(sv.y), a3 = bfhi(sv.y);
    float a4 = bflo(sv.z), a5 = bfhi(sv.z), a6 = bflo(sv.w), a7 = bfhi(sv.w);
    float c0 = 0.f, c1 = 0.f, c2 = 0.f, c3 = 0.f, c4 = 0.f, c5 = 0.f, c6 = 0.f, c7 = 0.f;

    #define IDX(ee) ((ee) < 16 ? __shfl(myidx0, (ee), 16) \
                   : (ee) < 32 ? __shfl(myidx1, (ee) - 16, 16) : csr_src[beg + (ee)])

    int e = 0;
    for (; e + 4 <= deg; e += 4) {
        int sn0 = IDX(e);
        int sn1 = IDX(e + 1);
        int sn2 = IDX(e + 2);
        int sn3 = IDX(e + 3);
        uint4 v0 = h4[(size_t)sn0 * 16 + l];
        uint4 v1 = h4[(size_t)sn1 * 16 + l];
        uint4 v2 = h4[(size_t)sn2 * 16 + l];
        uint4 v3 = h4[(size_t)sn3 * 16 + l];
        a0 += bflo(v0.x); a1 += bfhi(v0.x); a2 += bflo(v0.y); a3 += bfhi(v0.y);
        a4 += bflo(v0.z); a5 += bfhi(v0.z); a6 += bflo(v0.w); a7 += bfhi(v0.w);
        c0 += bflo(v1.x); c1 += bfhi(v1.x); c2 += bflo(v1.y); c3 += bfhi(v1.y);
        c4 += bflo(v1.z); c5 += bfhi(v1.z); c6 += bflo(v1.w); c7 += bfhi(v1.w);
        a0 += bflo(v2.x); a1 += bfhi(v2.x); a2 += bflo(v2.y); a3 += bfhi(v2.y);
        a4 += bflo(v2.z); a5 += bfhi(v2.z); a6 += bflo(v2.w); a7 += bfhi(v2.w);
        c0 += bflo(v3.x); c1 += bfhi(v3.x); c2 += bflo(v3.y); c3 += bfhi(v3.y);
        c4 += bflo(v3.z); c5 += bfhi(v3.z); c6 += bflo(v3.w); c7 += bfhi(v3.w);
    }
    for (; e < deg; ++e) {
        int sn = IDX(e);
        uint4 v = h4[(size_t)sn * 16 + l];
        a0 += bflo(v.x); a1 += bfhi(v.x); a2 += bflo(v.y); a3 += bfhi(v.y);
        a4 += bflo(v.z); a5 += bfhi(v.z); a6 += bflo(v.w); a7 += bfhi(v.w);
    }
    #undef IDX
    a0 += c0; a1 += c1; a2 += c2; a3 += c3;
    a4 += c4; a5 += c5; a6 += c6; a7 += c7;

    float dn = dinv[node];
    uint4 xv = ((const uint4*)xb)[(size_t)node * 16 + l];
    float4 bv0 = ((const float4*)bl)[2 * l];
    float4 bv1 = ((const float4*)bl)[2 * l + 1];
    float e0 = bflo(xv.x) + a0 * dn + bv0.x;
    float e1 = bfhi(xv.x) + a1 * dn + bv0.y;
    float e2 = bflo(xv.y) + a2 * dn + bv0.z;
    float e3 = bfhi(xv.y) + a3 * dn + bv0.w;
    float e4 = bflo(xv.z) + a4 * dn + bv1.x;
    float e5 = bfhi(xv.z) + a5 * dn + bv1.y;
    float e6 = bflo(xv.w) + a6 * dn + bv1.z;
    float e7 = bfhi(xv.w) + a7 * dn + bv1.w;

    float sum = e0 + e1 + e2 + e3 + e4 + e5 + e6 + e7;
    float sq = e0 * e0 + e1 * e1 + e2 * e2 + e3 * e3 + e4 * e4 + e5 * e5 + e6 * e6 + e7 * e7;
    #pragma unroll
    for (int o = 8; o > 0; o >>= 1) {
        sum += __shfl_xor(sum, o, 16);
        sq += __shfl_xor(sq, o, 16);
    }
    float mean = sum * (1.0f / DIM);
    float var = sq * (1.0f / DIM) - mean * mean;
    float rstd = rsqrtf(var + 1e-5f);
    float4 g0 = ((const float4*)gamma)[2 * l];
    float4 g1 = ((const float4*)gamma)[2 * l + 1];
    float4 t0 = ((const float4*)beta)[2 * l];
    float4 t1 = ((const float4*)beta)[2 * l + 1];
    float o0 = fmaxf((e0 - mean) * rstd * g0.x + t0.x, 0.f);
    float o1 = fmaxf((e1 - mean) * rstd * g0.y + t0.y, 0.f);
    float o2 = fmaxf((e2 - mean) * rstd * g0.z + t0.z, 0.f);
    float o3 = fmaxf((e3 - mean) * rstd * g0.w + t0.w, 0.f);
    float o4 = fmaxf((e4 - mean) * rstd * g1.x + t1.x, 0.f);
    float o5 = fmaxf((e5 - mean) * rstd * g1.y + t1.y, 0.f);
    float o6 = fmaxf((e6 - mean) * rstd * g1.z + t1.z, 0.f);
    float o7 = fmaxf((e7 - mean) * rstd * g1.w + t1.w, 0.f);
    uint4 ov;
    ov.x = bf2(o0, o1);
    ov.y = bf2(o2, o3);
    ov.z = bf2(o4, o5);
    ov.w = bf2(o6, o7);
    ((uint4*)xb)[(size_t)node * 16 + l] = ov;
}

// ---------------- global mean pool (batch is SORTED -> segments) ------------

__launch_bounds__(256)
__global__ void pool1_kernel(const u32* __restrict__ xb, const int* __restrict__ bounds,
                             float* __restrict__ partials) {
    __shared__ float part[3][DIM];
    int g = blockIdx.x >> 2;
    int q = blockIdx.x & 3;
    int beg = bounds[g], end = bounds[g + 1];
    int len = end - beg;
    int qbeg = beg + (int)(((long long)len * q) >> 2);
    int qend = beg + (int)(((long long)len * (q + 1)) >> 2);
    int grp = threadIdx.x >> 6;
    int lane = threadIdx.x & 63;
    float sx = 0.f, sy = 0.f;
    for (int r = qbeg + grp; r < qend; r += 4) {
        u32 v = xb[(size_t)r * 64 + lane];
        sx += bflo(v);
        sy += bfhi(v);
    }
    if (grp > 0) {
        part[grp - 1][lane * 2 + 0] = sx;
        part[grp - 1][lane * 2 + 1] = sy;
    }
    __syncthreads();
    if (grp == 0) {
        sx += part[0][lane * 2] + part[1][lane * 2] + part[2][lane * 2];
        sy += part[0][lane * 2 + 1] + part[1][lane * 2 + 1] + part[2][lane * 2 + 1];
        partials[(size_t)blockIdx.x * DIM + lane * 2 + 0] = sx;
        partials[(size_t)blockIdx.x * DIM + lane * 2 + 1] = sy;
    }
}

__launch_bounds__(256)
__global__ void pool2_kernel(const float* __restrict__ partials, const int* __restrict__ bounds,
                             float* __restrict__ out) {
    int t = blockIdx.x * 256 + threadIdx.x;
    if (t >= NGRAPH * DIM) return;
    int g = t >> 7;
    int d = t & 127;
    float s = partials[(size_t)(4 * g + 0) * DIM + d] + partials[(size_t)(4 * g + 1) * DIM + d] +
              partials[(size_t)(4 * g + 2) * DIM + d] + partials[(size_t)(4 * g + 3) * DIM + d];
    float cntf = (float)(bounds[g + 1] - bounds[g]);
    out[t] = s / fmaxf(cntf, 1.0f);
}

// ---------------- launch ----------------------------------------------------

extern "C" void kernel_launch(void* const* d_in, const int* in_sizes, int n_in,
                              void* d_out, int out_size, void* d_ws, size_t ws_size,
                              hipStream_t stream) {
    const float* x     = (const float*)d_in[0];
    const int*   ei    = (const int*)d_in[1];
    const int*   batch = (const int*)d_in[2];
    const float* W     = (const float*)d_in[3];
    const float* b     = (const float*)d_in[4];
    const float* gamma = (const float*)d_in[5];
    const float* beta  = (const float*)d_in[6];
    float* out = (float*)d_out;

    const int* srcE = ei;        // edge_index[0]
    const int* dstE = ei + NE;   // edge_index[1]

    // workspace layout
    char* p = (char*)d_ws;
    u32*   xb      = (u32*)p;    p += (size_t)NN * (DIM / 2) * sizeof(u32);    // 12.8 MB
    unsigned short* h2s = (unsigned short*)p; p += (size_t)NN * DIM * sizeof(unsigned short); // 12.8 MB
    unsigned short* WT  = (unsigned short*)p; p += (size_t)NLAYER * DIM * DIM * sizeof(unsigned short);
    float* dinv    = (float*)p;  p += (size_t)NN * sizeof(float);
    int*   deg     = (int*)p;    p += (size_t)NN * sizeof(int);
    int*   ccnt    = (int*)p;    p += (size_t)NN * sizeof(int);
    int*   row_ptr = (int*)p;    p += (size_t)(NN + 1) * sizeof(int);
    int*   csr_src = (int*)p;    p += (size_t)NE * sizeof(int);
    int*   bounds  = (int*)p;    p += (size_t)(NGRAPH + 1) * sizeof(int);
    int*   bsum    = (int*)p;    p += (size_t)SCAN_BLOCKS * sizeof(int);
    float* partials = (float*)p; p += (size_t)NGRAPH * POOL_SPLIT * DIM * sizeof(float);

    // prep (zero counters + bf16 conversions) then CSR build
    prep_kernel<<<(NN * 64 + NLAYER * DIM * DIM + 255) / 256, 256, 0, stream>>>(
        x, xb, W, WT, deg, ccnt);
    deg_kernel<<<(NE + 255) / 256, 256, 0, stream>>>(dstE, deg);
    blocksum_kernel<<<SCAN_BLOCKS, 256, 0, stream>>>(deg, bsum);
    scanb_bounds_kernel<<<2, 256, 0, stream>>>(bsum, batch, bounds);
    rowptr_kernel<<<SCAN_BLOCKS, 256, 0, stream>>>(deg, bsum, row_ptr, dinv);
    fill_kernel<<<(NE + 255) / 256, 256, 0, stream>>>(srcE, dstE, row_ptr, ccnt, csr_src);

    for (int l = 0; l < NLAYER; ++l) {
        gemm_mfma_kernel<<<(NN + 63) / 64, 256, 0, stream>>>(
            xb, WT + (size_t)l * DIM * DIM, dinv, h2s, NN);
        gather_ln_kernel<<<NN / 16, 256, 0, stream>>>(
            (const u32*)h2s, dinv, row_ptr, csr_src,
            b + l * DIM, gamma + l * DIM, beta + l * DIM, xb);
    }

    pool1_kernel<<<NGRAPH * POOL_SPLIT, 256, 0, stream>>>(xb, bounds, partials);
    pool2_kernel<<<(NGRAPH * DIM + 255) / 256, 256, 0, stream>>>(partials, bounds, out);
}

// Round 17
// 236.740 us; speedup vs baseline: 1.2844x; 1.0032x over previous
//
#include <hip/hip_runtime.h>

// N=50000 nodes, E=600000 edges, D=128, L=4 layers, G=128 graphs.
#define NN 50000
#define NE 600000
#define DIM 128
#define NLAYER 4
#define NGRAPH 128
#define SCAN_BLOCKS ((NN + 255) / 256)   // 196
#define XS_STRIDE 136                    // bf16 elems per LDS row (128 + 8 pad)
#define POOL_SPLIT 4                     // blocks per graph in pool stage 1

typedef unsigned int u32;
typedef __attribute__((ext_vector_type(8))) short short8v;  // 8 x bf16 (4 VGPR)
typedef __attribute__((ext_vector_type(4))) float f32x4;

// pack two fp32 -> 2x bf16 (round-to-nearest-even)
__device__ __forceinline__ u32 bf2(float a, float b) {
    u32 ua = __float_as_uint(a);
    ua = (ua + 0x7fffu + ((ua >> 16) & 1u)) >> 16;
    u32 ub = __float_as_uint(b);
    ub = (ub + 0x7fffu + ((ub >> 16) & 1u)) >> 16;
    return ua | (ub << 16);
}
__device__ __forceinline__ unsigned short bf16r(float a) {
    u32 u = __float_as_uint(a);
    u = (u + 0x7fffu + ((u >> 16) & 1u)) >> 16;
    return (unsigned short)u;
}
__device__ __forceinline__ float bflo(u32 v) { return __uint_as_float(v << 16); }
__device__ __forceinline__ float bfhi(u32 v) { return __uint_as_float(v & 0xffff0000u); }

// ---------------- prep: zero deg/ccnt + bf16 conversions (one launch) -------

__global__ void prep_kernel(const float* __restrict__ x, u32* __restrict__ xb,
                            const float* __restrict__ W, unsigned short* __restrict__ WT,
                            int* __restrict__ deg, int* __restrict__ ccnt) {
    int t = blockIdx.x * 256 + threadIdx.x;
    if (t < NN) {          // first 196 blocks also zero the CSR counters
        deg[t] = 0;
        ccnt[t] = 0;
    }
    if (t < NN * 64) {
        float2 v = ((const float2*)x)[t];
        xb[t] = bf2(v.x, v.y);
    } else {
        int u = t - NN * 64;
        if (u < NLAYER * DIM * DIM) {
            int l = u >> 14;
            int rem = u & 16383;
            int k = rem >> 7, n = rem & 127;
            WT[(size_t)l * 16384 + n * 128 + k] = bf16r(W[(size_t)l * 16384 + k * 128 + n]);
        }
    }
}

// ---------------- CSR build (edge structure only, once per launch) ----------

__global__ void deg_kernel(const int* __restrict__ dst, int* __restrict__ deg) {
    int e = blockIdx.x * blockDim.x + threadIdx.x;
    if (e < NE) atomicAdd(&deg[dst[e]], 1);
}

__launch_bounds__(256)
__global__ void blocksum_kernel(const int* __restrict__ deg, int* __restrict__ bsum) {
    int i = blockIdx.x * 256 + threadIdx.x;
    int v = (i < NN) ? deg[i] : 0;
    #pragma unroll
    for (int o = 32; o > 0; o >>= 1) v += __shfl_xor(v, o);
    __shared__ int ws[4];
    int wid = threadIdx.x >> 6;
    if ((threadIdx.x & 63) == 0) ws[wid] = v;
    __syncthreads();
    if (threadIdx.x == 0) bsum[blockIdx.x] = ws[0] + ws[1] + ws[2] + ws[3];
}

// block 0: exclusive scan of 196 block sums. block 1: graph segment bounds.
__launch_bounds__(256)
__global__ void scanb_bounds_kernel(int* __restrict__ bsum, const int* __restrict__ batch,
                                    int* __restrict__ bounds) {
    if (blockIdx.x == 0) {
        __shared__ int s[256];
        int tid = threadIdx.x;
        int v = (tid < SCAN_BLOCKS) ? bsum[tid] : 0;
        s[tid] = v;
        __syncthreads();
        for (int o = 1; o < 256; o <<= 1) {
            int t = (tid >= o) ? s[tid - o] : 0;
            __syncthreads();
            s[tid] += t;
            __syncthreads();
        }
        if (tid < SCAN_BLOCKS) bsum[tid] = s[tid] - v;  // exclusive
    } else {
        int g = threadIdx.x;
        if (g > NGRAPH) return;
        int lo = 0, hi = NN;
        while (lo < hi) {
            int mid = (lo + hi) >> 1;
            if (batch[mid] < g) lo = mid + 1; else hi = mid;
        }
        bounds[g] = lo;
    }
}

__launch_bounds__(256)
__global__ void rowptr_kernel(const int* __restrict__ deg, const int* __restrict__ bsum,
                              int* __restrict__ row_ptr, float* __restrict__ dinv) {
    __shared__ int s[256];
    int tid = threadIdx.x;
    int i = blockIdx.x * 256 + tid;
    int d = (i < NN) ? deg[i] : 0;
    s[tid] = d;
    __syncthreads();
    for (int o = 1; o < 256; o <<= 1) {
        int t = (tid >= o) ? s[tid - o] : 0;
        __syncthreads();
        s[tid] += t;
        __syncthreads();
    }
    if (i < NN) {
        row_ptr[i] = bsum[blockIdx.x] + s[tid] - d;  // exclusive prefix
        dinv[i] = rsqrtf((float)d + 1.0f);           // +1 self-loop
    }
    if (i == 0) row_ptr[NN] = NE;
}

__global__ void fill_kernel(const int* __restrict__ src, const int* __restrict__ dst,
                            const int* __restrict__ row_ptr, int* __restrict__ cnt,
                            int* __restrict__ csr_src) {
    int e = blockIdx.x * blockDim.x + threadIdx.x;
    if (e >= NE) return;
    int d = dst[e];
    int pos = row_ptr[d] + atomicAdd(&cnt[d], 1);
    csr_src[pos] = src[e];
}

// ---------------- GEMM via MFMA, hybrid staging ------------------------------
// H2[N,128](bf16) = (Xb @ W) * dinv[row]. 256 threads = 4 waves, 64-row tile.
// W staged in LDS (proven necessary: LDS-free B-loads cost +39 µs, R11/R12);
// A fragments loaded directly global->reg. LDS 34.8 KB -> 4 blocks/CU.
// Layouts (m89-verified): A row=lane&15, k=8*(lane>>4)+j; B col=lane&15,
// same k; D col=lane&15, row=4*(lane>>4)+reg.

__launch_bounds__(256)
__global__ void gemm_mfma_kernel(const u32* __restrict__ Xb, const unsigned short* __restrict__ WTl,
                                 const float* __restrict__ dinv,
                                 unsigned short* __restrict__ H2s, int nrows) {
    __shared__ __align__(16) unsigned short wt[128 * XS_STRIDE];   // 34816 B
    const int tid = threadIdx.x;
    const int wave = tid >> 6;
    const int lane = tid & 63;
    const int lrow = lane & 15;   // A row / B col within tile
    const int kg = lane >> 4;     // k-group: k = 32*kc + 8*kg + j

    // stage WT: 128 rows x 16 uint4 (LDS row stride 17 uint4)
    {
        const uint4* wg = (const uint4*)WTl;
        uint4* wt4 = (uint4*)wt;
        #pragma unroll
        for (int i = 0; i < 8; ++i) {
            int idx = i * 256 + tid;          // 0..2047
            int r = idx >> 4, c = idx & 15;
            wt4[r * 17 + c] = wg[idx];
        }
    }

    // A fragments direct from global (issued before barrier to overlap)
    const int row = blockIdx.x * 64 + wave * 16 + lrow;
    const int arow = min(row, nrows - 1);  // clamp OOB loads; stores guarded
    const short8v* xrow = (const short8v*)(Xb + (size_t)arow * 64);
    short8v a[4];
    #pragma unroll
    for (int kc = 0; kc < 4; ++kc) a[kc] = xrow[kc * 4 + kg];

    __syncthreads();

    f32x4 acc[8];
    #pragma unroll
    for (int t = 0; t < 8; ++t) acc[t] = (f32x4){0.f, 0.f, 0.f, 0.f};

    #pragma unroll
    for (int t = 0; t < 8; ++t) {
        #pragma unroll
        for (int kc = 0; kc < 4; ++kc) {
            short8v bfrag = *(const short8v*)&wt[(t * 16 + lrow) * XS_STRIDE + kc * 32 + kg * 8];
            acc[t] = __builtin_amdgcn_mfma_f32_16x16x32_bf16(a[kc], bfrag, acc[t], 0, 0, 0);
        }
    }

    const int rbase = blockIdx.x * 64 + wave * 16 + 4 * kg;
    #pragma unroll
    for (int r = 0; r < 4; ++r) {
        int orow = rbase + r;
        if (orow < nrows) {
            float dv = dinv[orow];
            #pragma unroll
            for (int t = 0; t < 8; ++t)
                H2s[(size_t)orow * DIM + t * 16 + lrow] = bf16r(acc[t][r] * dv);
        }
    }
}

// ---------------- fused gather + residual + bias + LayerNorm + ReLU ---------
// FOUR nodes per wave (16-lane groups); lane owns 8 dims via uint4 (16B).
// Edge loop unrolled x4 -> up to 16 rows in flight per wave.
// Index preload covers deg<=32 (P(deg>32|Poisson 12) ~ 2e-7): myidx0 for
// e<16, myidx1 for e<32; scalar fallback nearly never taken.

__launch_bounds__(256)
__global__ void gather_ln_kernel(const u32* __restrict__ h2u, const float* __restrict__ dinv,
                                 const int* __restrict__ row_ptr, const int* __restrict__ csr_src,
                                 const float* __restrict__ bl, const float* __restrict__ gamma,
                                 const float* __restrict__ beta, u32* __restrict__ xb) {
    int node = blockIdx.x * 16 + (threadIdx.x >> 4);
    int l = threadIdx.x & 15;
    int beg = row_ptr[node];
    int deg = row_ptr[node + 1] - beg;

    // preload up to 32 neighbor indices, two per lane of this 16-lane group
    int myidx0 = (l < deg) ? csr_src[beg + l] : 0;
    int myidx1 = (16 + l < deg) ? csr_src[beg + 16 + l] : 0;

    const uint4* h4 = (const uint4*)h2u;   // row = 16 uint4
    uint4 sv = h4[(size_t)node * 16 + l];  // self-loop term
    float a0 = bflo(sv.x), a1 = bfhi(sv.x), a2 = bflo(sv.y), a3 = bfhi(sv.y);
    float a4 = bflo(sv.z), a5 = bfhi(sv.z), a6 = bflo(sv.w), a7 = bfhi(sv.w);
    float c0 = 0.f, c1 = 0.f, c2 = 0.f, c3 = 0.f, c4 = 0.f, c5 = 0.f, c6 = 0.f, c7 = 0.f;

    #define IDX(ee) ((ee) < 16 ? __shfl(myidx0, (ee), 16) \
                   : (ee) < 32 ? __shfl(myidx1, (ee) - 16, 16) : csr_src[beg + (ee)])

    int e = 0;
    for (; e + 4 <= deg; e += 4) {
        int sn0 = IDX(e);
        int sn1 = IDX(e + 1);
        int sn2 = IDX(e + 2);
        int sn3 = IDX(e + 3);
        uint4 v0 = h4[(size_t)sn0 * 16 + l];
        uint4 v1 = h4[(size_t)sn1 * 16 + l];
        uint4 v2 = h4[(size_t)sn2 * 16 + l];
        uint4 v3 = h4[(size_t)sn3 * 16 + l];
        a0 += bflo(v0.x); a1 += bfhi(v0.x); a2 += bflo(v0.y); a3 += bfhi(v0.y);
        a4 += bflo(v0.z); a5 += bfhi(v0.z); a6 += bflo(v0.w); a7 += bfhi(v0.w);
        c0 += bflo(v1.x); c1 += bfhi(v1.x); c2 += bflo(v1.y); c3 += bfhi(v1.y);
        c4 += bflo(v1.z); c5 += bfhi(v1.z); c6 += bflo(v1.w); c7 += bfhi(v1.w);
        a0 += bflo(v2.x); a1 += bfhi(v2.x); a2 += bflo(v2.y); a3 += bfhi(v2.y);
        a4 += bflo(v2.z); a5 += bfhi(v2.z); a6 += bflo(v2.w); a7 += bfhi(v2.w);
        c0 += bflo(v3.x); c1 += bfhi(v3.x); c2 += bflo(v3.y); c3 += bfhi(v3.y);
        c4 += bflo(v3.z); c5 += bfhi(v3.z); c6 += bflo(v3.w); c7 += bfhi(v3.w);
    }
    for (; e < deg; ++e) {
        int sn = IDX(e);
        uint4 v = h4[(size_t)sn * 16 + l];
        a0 += bflo(v.x); a1 += bfhi(v.x); a2 += bflo(v.y); a3 += bfhi(v.y);
        a4 += bflo(v.z); a5 += bfhi(v.z); a6 += bflo(v.w); a7 += bfhi(v.w);
    }
    #undef IDX
    a0 += c0; a1 += c1; a2 += c2; a3 += c3;
    a4 += c4; a5 += c5; a6 += c6; a7 += c7;

    float dn = dinv[node];
    uint4 xv = ((const uint4*)xb)[(size_t)node * 16 + l];
    float4 bv0 = ((const float4*)bl)[2 * l];
    float4 bv1 = ((const float4*)bl)[2 * l + 1];
    float e0 = bflo(xv.x) + a0 * dn + bv0.x;
    float e1 = bfhi(xv.x) + a1 * dn + bv0.y;
    float e2 = bflo(xv.y) + a2 * dn + bv0.z;
    float e3 = bfhi(xv.y) + a3 * dn + bv0.w;
    float e4 = bflo(xv.z) + a4 * dn + bv1.x;
    float e5 = bfhi(xv.z) + a5 * dn + bv1.y;
    float e6 = bflo(xv.w) + a6 * dn + bv1.z;
    float e7 = bfhi(xv.w) + a7 * dn + bv1.w;

    float sum = e0 + e1 + e2 + e3 + e4 + e5 + e6 + e7;
    float sq = e0 * e0 + e1 * e1 + e2 * e2 + e3 * e3 + e4 * e4 + e5 * e5 + e6 * e6 + e7 * e7;
    #pragma unroll
    for (int o = 8; o > 0; o >>= 1) {
        sum += __shfl_xor(sum, o, 16);
        sq += __shfl_xor(sq, o, 16);
    }
    float mean = sum * (1.0f / DIM);
    float var = sq * (1.0f / DIM) - mean * mean;
    float rstd = rsqrtf(var + 1e-5f);
    float4 g0 = ((const float4*)gamma)[2 * l];
    float4 g1 = ((const float4*)gamma)[2 * l + 1];
    float4 t0 = ((const float4*)beta)[2 * l];
    float4 t1 = ((const float4*)beta)[2 * l + 1];
    float o0 = fmaxf((e0 - mean) * rstd * g0.x + t0.x, 0.f);
    float o1 = fmaxf((e1 - mean) * rstd * g0.y + t0.y, 0.f);
    float o2 = fmaxf((e2 - mean) * rstd * g0.z + t0.z, 0.f);
    float o3 = fmaxf((e3 - mean) * rstd * g0.w + t0.w, 0.f);
    float o4 = fmaxf((e4 - mean) * rstd * g1.x + t1.x, 0.f);
    float o5 = fmaxf((e5 - mean) * rstd * g1.y + t1.y, 0.f);
    float o6 = fmaxf((e6 - mean) * rstd * g1.z + t1.z, 0.f);
    float o7 = fmaxf((e7 - mean) * rstd * g1.w + t1.w, 0.f);
    uint4 ov;
    ov.x = bf2(o0, o1);
    ov.y = bf2(o2, o3);
    ov.z = bf2(o4, o5);
    ov.w = bf2(o6, o7);
    ((uint4*)xb)[(size_t)node * 16 + l] = ov;
}

// ---------------- global mean pool (batch is SORTED -> segments) ------------

__launch_bounds__(256)
__global__ void pool1_kernel(const u32* __restrict__ xb, const int* __restrict__ bounds,
                             float* __restrict__ partials) {
    __shared__ float part[3][DIM];
    int g = blockIdx.x >> 2;
    int q = blockIdx.x & 3;
    int beg = bounds[g], end = bounds[g + 1];
    int len = end - beg;
    int qbeg = beg + (int)(((long long)len * q) >> 2);
    int qend = beg + (int)(((long long)len * (q + 1)) >> 2);
    int grp = threadIdx.x >> 6;
    int lane = threadIdx.x & 63;
    float sx = 0.f, sy = 0.f;
    for (int r = qbeg + grp; r < qend; r += 4) {
        u32 v = xb[(size_t)r * 64 + lane];
        sx += bflo(v);
        sy += bfhi(v);
    }
    if (grp > 0) {
        part[grp - 1][lane * 2 + 0] = sx;
        part[grp - 1][lane * 2 + 1] = sy;
    }
    __syncthreads();
    if (grp == 0) {
        sx += part[0][lane * 2] + part[1][lane * 2] + part[2][lane * 2];
        sy += part[0][lane * 2 + 1] + part[1][lane * 2 + 1] + part[2][lane * 2 + 1];
        partials[(size_t)blockIdx.x * DIM + lane * 2 + 0] = sx;
        partials[(size_t)blockIdx.x * DIM + lane * 2 + 1] = sy;
    }
}

__launch_bounds__(256)
__global__ void pool2_kernel(const float* __restrict__ partials, const int* __restrict__ bounds,
                             float* __restrict__ out) {
    int t = blockIdx.x * 256 + threadIdx.x;
    if (t >= NGRAPH * DIM) return;
    int g = t >> 7;
    int d = t & 127;
    float s = partials[(size_t)(4 * g + 0) * DIM + d] + partials[(size_t)(4 * g + 1) * DIM + d] +
              partials[(size_t)(4 * g + 2) * DIM + d] + partials[(size_t)(4 * g + 3) * DIM + d];
    float cntf = (float)(bounds[g + 1] - bounds[g]);
    out[t] = s / fmaxf(cntf, 1.0f);
}

// ---------------- launch ----------------------------------------------------

extern "C" void kernel_launch(void* const* d_in, const int* in_sizes, int n_in,
                              void* d_out, int out_size, void* d_ws, size_t ws_size,
                              hipStream_t stream) {
    const float* x     = (const float*)d_in[0];
    const int*   ei    = (const int*)d_in[1];
    const int*   batch = (const int*)d_in[2];
    const float* W     = (const float*)d_in[3];
    const float* b     = (const float*)d_in[4];
    const float* gamma = (const float*)d_in[5];
    const float* beta  = (const float*)d_in[6];
    float* out = (float*)d_out;

    const int* srcE = ei;        // edge_index[0]
    const int* dstE = ei + NE;   // edge_index[1]

    // workspace layout
    char* p = (char*)d_ws;
    u32*   xb      = (u32*)p;    p += (size_t)NN * (DIM / 2) * sizeof(u32);    // 12.8 MB
    unsigned short* h2s = (unsigned short*)p; p += (size_t)NN * DIM * sizeof(unsigned short); // 12.8 MB
    unsigned short* WT  = (unsigned short*)p; p += (size_t)NLAYER * DIM * DIM * sizeof(unsigned short);
    float* dinv    = (float*)p;  p += (size_t)NN * sizeof(float);
    int*   deg     = (int*)p;    p += (size_t)NN * sizeof(int);
    int*   ccnt    = (int*)p;    p += (size_t)NN * sizeof(int);
    int*   row_ptr = (int*)p;    p += (size_t)(NN + 1) * sizeof(int);
    int*   csr_src = (int*)p;    p += (size_t)NE * sizeof(int);
    int*   bounds  = (int*)p;    p += (size_t)(NGRAPH + 1) * sizeof(int);
    int*   bsum    = (int*)p;    p += (size_t)SCAN_BLOCKS * sizeof(int);
    float* partials = (float*)p; p += (size_t)NGRAPH * POOL_SPLIT * DIM * sizeof(float);

    // prep (zero counters + bf16 conversions) then CSR build
    prep_kernel<<<(NN * 64 + NLAYER * DIM * DIM + 255) / 256, 256, 0, stream>>>(
        x, xb, W, WT, deg, ccnt);
    deg_kernel<<<(NE + 255) / 256, 256, 0, stream>>>(dstE, deg);
    blocksum_kernel<<<SCAN_BLOCKS, 256, 0, stream>>>(deg, bsum);
    scanb_bounds_kernel<<<2, 256, 0, stream>>>(bsum, batch, bounds);
    rowptr_kernel<<<SCAN_BLOCKS, 256, 0, stream>>>(deg, bsum, row_ptr, dinv);
    fill_kernel<<<(NE + 255) / 256, 256, 0, stream>>>(srcE, dstE, row_ptr, ccnt, csr_src);

    for (int l = 0; l < NLAYER; ++l) {
        gemm_mfma_kernel<<<(NN + 63) / 64, 256, 0, stream>>>(
            xb, WT + (size_t)l * DIM * DIM, dinv, h2s, NN);
        gather_ln_kernel<<<NN / 16, 256, 0, stream>>>(
            (const u32*)h2s, dinv, row_ptr, csr_src,
            b + l * DIM, gamma + l * DIM, beta + l * DIM, xb);
    }

    pool1_kernel<<<NGRAPH * POOL_SPLIT, 256, 0, stream>>>(xb, bounds, partials);
    pool2_kernel<<<(NGRAPH * DIM + 255) / 256, 256, 0, stream>>>(partials, bounds, out);
}